// Round 1
// baseline (450.380 us; speedup 1.0000x reference)
//
#include <hip/hip_runtime.h>
#include <hip/hip_bf16.h>

using bf16 = __bf16;
typedef __bf16 bf16x8 __attribute__((ext_vector_type(8)));
typedef float f32x4 __attribute__((ext_vector_type(4)));

__device__ __forceinline__ void gload_lds16(const bf16* g, bf16* l) {
  __builtin_amdgcn_global_load_lds(
      (const __attribute__((address_space(1))) void*)g,
      (__attribute__((address_space(3))) void*)l, 16, 0, 0);
}

// fp32 -> bf16 (RNE via hardware cvt), 8 elems/thread
__global__ __launch_bounds__(256) void cvt_f32_bf16(const float* __restrict__ in,
                                                    bf16* __restrict__ out, int n) {
  int i = (blockIdx.x * 256 + threadIdx.x) * 8;
  if (i >= n) return;
  float4 f0 = *(const float4*)&in[i];
  float4 f1 = *(const float4*)&in[i + 4];
  bf16x8 o;
  o[0] = (bf16)f0.x; o[1] = (bf16)f0.y; o[2] = (bf16)f0.z; o[3] = (bf16)f0.w;
  o[4] = (bf16)f1.x; o[5] = (bf16)f1.y; o[6] = (bf16)f1.z; o[7] = (bf16)f1.w;
  *(bf16x8*)&out[i] = o;
}

// C = scale * A @ B^T (+ Add, fp32 out, for EPI==2). A: MxK row-major (lda),
// B^T operand given as B: NxK row-major (ldb). 128x128 tile, 4 waves (2x2),
// BK=32, single-buffered LDS staged via global_load_lds width 16.
// EPI 0: bf16 C. EPI 2: fp32 C = acc*scale + Add.
template <int EPI>
__global__ __launch_bounds__(256)
void gemm_bt(const bf16* __restrict__ A, const bf16* __restrict__ B,
             void* __restrict__ Cv, const float* __restrict__ Add,
             int K, int lda, int ldb, int ldc,
             long sA, long sB, long sC, long sAdd, float scale) {
  const int z = blockIdx.z;
  A += (long)z * sA;
  B += (long)z * sB;
  const int tid = threadIdx.x;
  const int wave = tid >> 6;
  const int lane = tid & 63;
  const int wr = wave >> 1, wc = wave & 1;
  const long brow = (long)blockIdx.x * 128;
  const long bcol = (long)blockIdx.y * 128;

  __shared__ bf16 As[128 * 32];
  __shared__ bf16 Bs[128 * 32];

  f32x4 acc[4][4] = {};

  const int r0 = tid >> 2;          // 0..63
  const int c0 = (tid & 3) * 8;     // 0,8,16,24
  const bf16* ga = A + (brow + r0) * (long)lda + c0;
  const bf16* gb = B + (bcol + r0) * (long)ldb + c0;
  bf16* la0 = As + tid * 8;
  bf16* la1 = As + 2048 + tid * 8;
  bf16* lb0 = Bs + tid * 8;
  bf16* lb1 = Bs + 2048 + tid * 8;

  // fragment base offsets in LDS (elements): row = (lane&15), k = (lane>>4)*8
  const int afo = (wr * 64 + (lane & 15)) * 32 + (lane >> 4) * 8;
  const int bfo = (wc * 64 + (lane & 15)) * 32 + (lane >> 4) * 8;

  const int nk = K >> 5;
  for (int kt = 0; kt < nk; ++kt) {
    gload_lds16(ga, la0);
    gload_lds16(ga + (long)64 * lda, la1);
    gload_lds16(gb, lb0);
    gload_lds16(gb + (long)64 * ldb, lb1);
    ga += 32; gb += 32;
    __syncthreads();
    bf16x8 av[4], bv[4];
#pragma unroll
    for (int i = 0; i < 4; ++i) {
      av[i] = *(const bf16x8*)&As[afo + i * 512];
      bv[i] = *(const bf16x8*)&Bs[bfo + i * 512];
    }
#pragma unroll
    for (int mi = 0; mi < 4; ++mi)
#pragma unroll
      for (int ni = 0; ni < 4; ++ni)
        acc[mi][ni] = __builtin_amdgcn_mfma_f32_16x16x32_bf16(av[mi], bv[ni],
                                                              acc[mi][ni], 0, 0, 0);
    __syncthreads();
  }

  // C/D layout (m89-verified): col = lane&15, row = (lane>>4)*4 + j
  const int or0 = wr * 64 + ((lane >> 4) << 2);
  const int oc0 = wc * 64 + (lane & 15);
#pragma unroll
  for (int mi = 0; mi < 4; ++mi) {
#pragma unroll
    for (int ni = 0; ni < 4; ++ni) {
#pragma unroll
      for (int j = 0; j < 4; ++j) {
        const long row = brow + or0 + mi * 16 + j;
        const long col = bcol + oc0 + ni * 16;
        const float vres = acc[mi][ni][j] * scale;
        if constexpr (EPI == 0) {
          bf16* C = (bf16*)Cv + (long)z * sC;
          C[row * ldc + col] = (bf16)vres;
        } else {
          float* C = (float*)Cv + (long)z * sC;
          const float* Ad = Add + (long)z * sAdd;
          C[row * ldc + col] = vres + Ad[row * ldc + col];
        }
      }
    }
  }
}

// in-place row softmax over rows of length 2048 (bf16)
__global__ __launch_bounds__(256) void softmax_rows(bf16* __restrict__ S) {
  const long row = blockIdx.x;
  bf16* p = S + row * 2048;
  const int tid = threadIdx.x;
  bf16x8 v = *(const bf16x8*)&p[tid * 8];
  float x[8];
  float m = -1e30f;
#pragma unroll
  for (int i = 0; i < 8; ++i) { x[i] = (float)v[i]; m = fmaxf(m, x[i]); }
#pragma unroll
  for (int off = 32; off > 0; off >>= 1) m = fmaxf(m, __shfl_xor(m, off, 64));
  __shared__ float red[4];
  __shared__ float red2[4];
  if ((tid & 63) == 0) red[tid >> 6] = m;
  __syncthreads();
  m = fmaxf(fmaxf(red[0], red[1]), fmaxf(red[2], red[3]));
  float e[8];
  float s = 0.f;
#pragma unroll
  for (int i = 0; i < 8; ++i) { e[i] = __expf(x[i] - m); s += e[i]; }
#pragma unroll
  for (int off = 32; off > 0; off >>= 1) s += __shfl_xor(s, off, 64);
  if ((tid & 63) == 0) red2[tid >> 6] = s;
  __syncthreads();
  s = red2[0] + red2[1] + red2[2] + red2[3];
  const float inv = 1.0f / s;
  bf16x8 o;
#pragma unroll
  for (int i = 0; i < 8; ++i) o[i] = (bf16)(e[i] * inv);
  *(bf16x8*)&p[tid * 8] = o;
}

extern "C" void kernel_launch(void* const* d_in, const int* in_sizes, int n_in,
                              void* d_out, int out_size, void* d_ws, size_t ws_size,
                              hipStream_t stream) {
  const float* q_in = (const float*)d_in[0];  // (8,2048,1024)
  const float* k_in = (const float*)d_in[1];  // (8,2048,1024)
  const float* Wq   = (const float*)d_in[2];  // (1024,1024) row-major (out,in)
  const float* Wk   = (const float*)d_in[3];
  const float* Wv   = (const float*)d_in[4];
  float* out = (float*)d_out;
  char* ws = (char*)d_ws;

  // ws layout (bytes); S reuses the qb+kb region after projections are done.
  bf16* qb  = (bf16*)(ws);                 // 33,554,432 B
  bf16* kb  = (bf16*)(ws + 33554432);      // 33,554,432 B
  bf16* S   = (bf16*)(ws);                 // 67,108,864 B (reuse)
  bf16* Wqb = (bf16*)(ws + 67108864);      // 2,097,152 B
  bf16* Wkb = (bf16*)(ws + 69206016);
  bf16* Wvb = (bf16*)(ws + 71303168);
  bf16* Qp  = (bf16*)(ws + 73400320);      // 33,554,432 B
  bf16* Kp  = (bf16*)(ws + 106954752);
  bf16* Vpt = (bf16*)(ws + 140509184);     // (b,1024,2048) = Vp^T per batch

  // 1) fp32 -> bf16
  cvt_f32_bf16<<<8192, 256, 0, stream>>>(q_in, qb, 16777216);
  cvt_f32_bf16<<<8192, 256, 0, stream>>>(k_in, kb, 16777216);
  cvt_f32_bf16<<<512, 256, 0, stream>>>(Wq, Wqb, 1048576);
  cvt_f32_bf16<<<512, 256, 0, stream>>>(Wk, Wkb, 1048576);
  cvt_f32_bf16<<<512, 256, 0, stream>>>(Wv, Wvb, 1048576);

  // 2) Qp = qb @ Wq^T  (M=16384, N=1024, K=1024)
  gemm_bt<0><<<dim3(128, 8, 1), 256, 0, stream>>>(
      qb, Wqb, Qp, nullptr, 1024, 1024, 1024, 1024, 0, 0, 0, 0, 1.0f);
  //    Kp = kb @ Wk^T
  gemm_bt<0><<<dim3(128, 8, 1), 256, 0, stream>>>(
      kb, Wkb, Kp, nullptr, 1024, 1024, 1024, 1024, 0, 0, 0, 0, 1.0f);
  //    Vpt[b] = Wv @ qb[b]^T  (M=1024, N=2048, K=1024) -> (b,1024,2048)
  gemm_bt<0><<<dim3(8, 16, 8), 256, 0, stream>>>(
      Wvb, qb, Vpt, nullptr, 1024, 1024, 1024, 2048,
      0L, 2097152L, 2097152L, 0L, 1.0f);

  // 3) S[b] = Kp[b] @ Qp[b]^T / 32  (M=2048, N=2048, K=1024)
  gemm_bt<0><<<dim3(16, 16, 8), 256, 0, stream>>>(
      Kp, Qp, S, nullptr, 1024, 1024, 1024, 2048,
      2097152L, 2097152L, 4194304L, 0L, 0.03125f);

  // 4) row softmax over last axis (2048), in place
  softmax_rows<<<16384, 256, 0, stream>>>(S);

  // 5) out[b] = P[b] @ Vp[b] + key_input[b]  (M=2048, N=1024, K=2048), fp32
  gemm_bt<2><<<dim3(16, 8, 8), 256, 0, stream>>>(
      S, Vpt, out, k_in, 2048, 2048, 2048, 1024,
      4194304L, 2097152L, 2097152L, 2097152L, 1.0f);
}

// Round 2
// 339.996 us; speedup vs baseline: 1.3247x; 1.3247x over previous
//
#include <hip/hip_runtime.h>
#include <hip/hip_bf16.h>

using bf16 = __bf16;
typedef __bf16 bf16x8 __attribute__((ext_vector_type(8)));
typedef float f32x4 __attribute__((ext_vector_type(4)));

__device__ __forceinline__ void gload_lds16(const bf16* g, bf16* l) {
  __builtin_amdgcn_global_load_lds(
      (const __attribute__((address_space(1))) void*)g,
      (__attribute__((address_space(3))) void*)l, 16, 0, 0);
}

// fp32 -> bf16, 8 elems/thread
__global__ __launch_bounds__(256) void cvt_f32_bf16(const float* __restrict__ in,
                                                    bf16* __restrict__ out, int n) {
  int i = (blockIdx.x * 256 + threadIdx.x) * 8;
  if (i >= n) return;
  float4 f0 = *(const float4*)&in[i];
  float4 f1 = *(const float4*)&in[i + 4];
  bf16x8 o;
  o[0] = (bf16)f0.x; o[1] = (bf16)f0.y; o[2] = (bf16)f0.z; o[3] = (bf16)f0.w;
  o[4] = (bf16)f1.x; o[5] = (bf16)f1.y; o[6] = (bf16)f1.z; o[7] = (bf16)f1.w;
  *(bf16x8*)&out[i] = o;
}

// C = scale * A @ B^T (+ Add for EPI==2, fp32 out).
// 256x256 tile, BK=32, 8 waves (2x4), per-wave 128x64 output.
// 4-buffer cyclic LDS pipeline: iter t computes buf[t%4], stages K-tile t+3
// into buf[(t+3)%4] (= buf[(t-1)%4], last read one full iter ago -> race-free).
// Counted vmcnt(8) (2 tiles in flight), raw s_barrier (no vmcnt drain).
// LDS chunk-XOR swizzle (c ^= (row>>1)&3) on both stage-source and ds_read
// keeps global loads coalesced and makes frag reads bank-conflict-free.
// Requires: M%256==0, N%256==0, K%32==0, K>=128.
template <int EPI>
__global__ __launch_bounds__(512, 2)
void gemm_bt(const bf16* __restrict__ A, const bf16* __restrict__ B,
             void* __restrict__ Cv, const float* __restrict__ Add,
             int K, int lda, int ldb, int ldc,
             long sA, long sB, long sC, long sAdd, float scale) {
  const int z = blockIdx.z;
  A += (long)z * sA;
  B += (long)z * sB;
  const int tid = threadIdx.x;
  const int lane = tid & 63;
  const int wave = tid >> 6;
  const int wr = wave >> 2;        // 0..1
  const int wc = wave & 3;         // 0..3
  const long brow = (long)blockIdx.x * 256;
  const long bcol = (long)blockIdx.y * 256;

  __shared__ bf16 lds[4][16384];   // 4 bufs x 32KB: A[256][32] then B[256][32]

  f32x4 acc[8][4] = {};

  // ---- staging setup: 4 loads/thread/K-tile (A rows 0-127,128-255; B same)
  const int srow = tid >> 2;                      // 0..127
  const int scg  = (tid & 3) ^ ((srow >> 1) & 3); // swizzled k-chunk (same for row+128)
  const bf16* gA = A + (brow + srow) * (long)lda + scg * 8;
  const bf16* gB = B + (bcol + srow) * (long)ldb + scg * 8;
  const long a128 = (long)lda << 7;
  const long b128 = (long)ldb << 7;

  const int nk = K >> 5;

  auto stageA = [&](int t) {
    bf16* buf = lds[t & 3];
    const bf16* g = gA + (long)t * 32;
    gload_lds16(g,        buf + tid * 8);
    gload_lds16(g + a128, buf + 4096 + tid * 8);
  };
  auto stageB = [&](int t) {
    bf16* buf = lds[t & 3];
    const bf16* g = gB + (long)t * 32;
    gload_lds16(g,        buf + 8192 + tid * 8);
    gload_lds16(g + b128, buf + 12288 + tid * 8);
  };

  // ---- prologue: stage K-tiles 0,1,2 (12 loads); wait tile 0 (leave 8)
  stageA(0); stageB(0);
  stageA(1); stageB(1);
  stageA(2); stageB(2);
  asm volatile("s_waitcnt vmcnt(8)" ::: "memory");
  __builtin_amdgcn_s_barrier();

  const int lk = lane >> 4;   // 0..3 (k-chunk)
  const int lr = lane & 15;   // row-within-frag

  for (int t = 0; t < nk; ++t) {
    bf16* buf = lds[t & 3];
    bf16x8 av[8], bv[4];
    // ---- phase 0: read av[0..3] + all bv, stage A-half of tile t+3
#pragma unroll
    for (int mi = 0; mi < 4; ++mi) {
      const int r = wr * 128 + mi * 16 + lr;
      av[mi] = *(const bf16x8*)&buf[r * 32 + ((lk ^ ((r >> 1) & 3)) << 3)];
    }
#pragma unroll
    for (int ni = 0; ni < 4; ++ni) {
      const int r = wc * 64 + ni * 16 + lr;
      bv[ni] = *(const bf16x8*)&buf[8192 + r * 32 + ((lk ^ ((r >> 1) & 3)) << 3)];
    }
    if (t + 3 < nk) stageA(t + 3);
    __builtin_amdgcn_s_setprio(1);
#pragma unroll
    for (int mi = 0; mi < 4; ++mi)
#pragma unroll
      for (int ni = 0; ni < 4; ++ni)
        acc[mi][ni] = __builtin_amdgcn_mfma_f32_16x16x32_bf16(av[mi], bv[ni],
                                                              acc[mi][ni], 0, 0, 0);
    __builtin_amdgcn_s_setprio(0);
    __builtin_amdgcn_s_barrier();
    // ---- phase 1: read av[4..7], stage B-half of tile t+3
#pragma unroll
    for (int mi = 4; mi < 8; ++mi) {
      const int r = wr * 128 + mi * 16 + lr;
      av[mi] = *(const bf16x8*)&buf[r * 32 + ((lk ^ ((r >> 1) & 3)) << 3)];
    }
    if (t + 3 < nk) stageB(t + 3);
    __builtin_amdgcn_s_setprio(1);
#pragma unroll
    for (int mi = 4; mi < 8; ++mi)
#pragma unroll
      for (int ni = 0; ni < 4; ++ni)
        acc[mi][ni] = __builtin_amdgcn_mfma_f32_16x16x32_bf16(av[mi], bv[ni],
                                                              acc[mi][ni], 0, 0, 0);
    __builtin_amdgcn_s_setprio(0);
    // counted drain: keep 2 tiles (8 loads) in flight; taper at tail
    if (t < nk - 3)       { asm volatile("s_waitcnt vmcnt(8)" ::: "memory"); }
    else if (t == nk - 3) { asm volatile("s_waitcnt vmcnt(4)" ::: "memory"); }
    else if (t == nk - 2) { asm volatile("s_waitcnt vmcnt(0)" ::: "memory"); }
    __builtin_amdgcn_s_barrier();
  }

  // ---- epilogue. C/D layout: col = lane&15, row = (lane>>4)*4 + j
  const int or0 = wr * 128 + ((lane >> 4) << 2);
  const int oc0 = wc * 64 + (lane & 15);
#pragma unroll
  for (int mi = 0; mi < 8; ++mi) {
#pragma unroll
    for (int ni = 0; ni < 4; ++ni) {
#pragma unroll
      for (int j = 0; j < 4; ++j) {
        const long row = brow + or0 + mi * 16 + j;
        const long col = bcol + oc0 + ni * 16;
        const float vres = acc[mi][ni][j] * scale;
        if constexpr (EPI == 0) {
          bf16* C = (bf16*)Cv + (long)z * sC;
          C[row * ldc + col] = (bf16)vres;
        } else {
          float* C = (float*)Cv + (long)z * sC;
          const float* Ad = Add + (long)z * sAdd;
          C[row * ldc + col] = vres + Ad[row * ldc + col];
        }
      }
    }
  }
}

// in-place row softmax over rows of length 2048 (bf16)
__global__ __launch_bounds__(256) void softmax_rows(bf16* __restrict__ S) {
  const long row = blockIdx.x;
  bf16* p = S + row * 2048;
  const int tid = threadIdx.x;
  bf16x8 v = *(const bf16x8*)&p[tid * 8];
  float x[8];
  float m = -1e30f;
#pragma unroll
  for (int i = 0; i < 8; ++i) { x[i] = (float)v[i]; m = fmaxf(m, x[i]); }
#pragma unroll
  for (int off = 32; off > 0; off >>= 1) m = fmaxf(m, __shfl_xor(m, off, 64));
  __shared__ float red[4];
  __shared__ float red2[4];
  if ((tid & 63) == 0) red[tid >> 6] = m;
  __syncthreads();
  m = fmaxf(fmaxf(red[0], red[1]), fmaxf(red[2], red[3]));
  float e[8];
  float s = 0.f;
#pragma unroll
  for (int i = 0; i < 8; ++i) { e[i] = __expf(x[i] - m); s += e[i]; }
#pragma unroll
  for (int off = 32; off > 0; off >>= 1) s += __shfl_xor(s, off, 64);
  if ((tid & 63) == 0) red2[tid >> 6] = s;
  __syncthreads();
  s = red2[0] + red2[1] + red2[2] + red2[3];
  const float inv = 1.0f / s;
  bf16x8 o;
#pragma unroll
  for (int i = 0; i < 8; ++i) o[i] = (bf16)(e[i] * inv);
  *(bf16x8*)&p[tid * 8] = o;
}

extern "C" void kernel_launch(void* const* d_in, const int* in_sizes, int n_in,
                              void* d_out, int out_size, void* d_ws, size_t ws_size,
                              hipStream_t stream) {
  const float* q_in = (const float*)d_in[0];  // (8,2048,1024)
  const float* k_in = (const float*)d_in[1];  // (8,2048,1024)
  const float* Wq   = (const float*)d_in[2];  // (1024,1024)
  const float* Wk   = (const float*)d_in[3];
  const float* Wv   = (const float*)d_in[4];
  float* out = (float*)d_out;
  char* ws = (char*)d_ws;

  bf16* qb  = (bf16*)(ws);                 // 33,554,432 B
  bf16* kb  = (bf16*)(ws + 33554432);      // 33,554,432 B
  bf16* S   = (bf16*)(ws);                 // 67,108,864 B (reuse of qb+kb)
  bf16* Wqb = (bf16*)(ws + 67108864);
  bf16* Wkb = (bf16*)(ws + 69206016);
  bf16* Wvb = (bf16*)(ws + 71303168);
  bf16* Qp  = (bf16*)(ws + 73400320);
  bf16* Kp  = (bf16*)(ws + 106954752);
  bf16* Vpt = (bf16*)(ws + 140509184);     // (b,1024,2048) = Vp^T per batch

  cvt_f32_bf16<<<8192, 256, 0, stream>>>(q_in, qb, 16777216);
  cvt_f32_bf16<<<8192, 256, 0, stream>>>(k_in, kb, 16777216);
  cvt_f32_bf16<<<512, 256, 0, stream>>>(Wq, Wqb, 1048576);
  cvt_f32_bf16<<<512, 256, 0, stream>>>(Wk, Wkb, 1048576);
  cvt_f32_bf16<<<512, 256, 0, stream>>>(Wv, Wvb, 1048576);

  // Qp = qb @ Wq^T  (M=16384, N=1024, K=1024)
  gemm_bt<0><<<dim3(64, 4, 1), 512, 0, stream>>>(
      qb, Wqb, Qp, nullptr, 1024, 1024, 1024, 1024, 0, 0, 0, 0, 1.0f);
  // Kp = kb @ Wk^T
  gemm_bt<0><<<dim3(64, 4, 1), 512, 0, stream>>>(
      kb, Wkb, Kp, nullptr, 1024, 1024, 1024, 1024, 0, 0, 0, 0, 1.0f);
  // Vpt[b] = Wv @ qb[b]^T  (M=1024, N=2048, K=1024)
  gemm_bt<0><<<dim3(4, 8, 8), 512, 0, stream>>>(
      Wvb, qb, Vpt, nullptr, 1024, 1024, 1024, 2048,
      0L, 2097152L, 2097152L, 0L, 1.0f);

  // S[b] = Kp[b] @ Qp[b]^T / 32  (M=2048, N=2048, K=1024)
  gemm_bt<0><<<dim3(8, 8, 8), 512, 0, stream>>>(
      Kp, Qp, S, nullptr, 1024, 1024, 1024, 2048,
      2097152L, 2097152L, 4194304L, 0L, 0.03125f);

  // row softmax (axis n_q), in place
  softmax_rows<<<16384, 256, 0, stream>>>(S);

  // out[b] = P[b] @ Vpt[b]^T' + key_input[b]  (M=2048, N=1024, K=2048), fp32
  gemm_bt<2><<<dim3(8, 4, 8), 512, 0, stream>>>(
      S, Vpt, out, k_in, 2048, 2048, 2048, 1024,
      4194304L, 2097152L, 2097152L, 2097152L, 1.0f);
}